// Round 6
// baseline (337.186 us; speedup 1.0000x reference)
//
#include <hip/hip_runtime.h>
#include <stdint.h>
#include <math.h>

// Problem constants
constexpr int Nn  = 32768;          // B*H*W = 32*32*32
constexpr int Kk  = 1024;

// d_out layout (floats)
constexpr int OUT0_N   = 32 * 64 * 1024;       // 2097152 (z_st, [B,D,H,W])
constexpr int OUT_LOSS = OUT0_N;               // 2097152
constexpr int OUT_PERP = OUT0_N + 1;           // 2097153
constexpr int OUT_ENC  = OUT0_N + 2;           // 2097154

// d_ws layout (bytes):
//   [0     .. 65536)  loss partials double[8192] (fully written by finish)
//   [65536 .. 327680) minkey u64[32768]          (memset 0xFF)
// R4 lesson: no single-address atomics at grid scale.
constexpr size_t WS_LP  = 0;
constexpr size_t WS_KEY = 65536;

// ---------------------------------------------------------------------------
// numpy-bit-exact 64-elem squared-norm: tt[d]=fl(x*x), 8 stride-8 sequential
// accumulators, pairwise combine. Contraction OFF. Contiguous variant (global
// emb rows) and stride-128-float4 variant (xs[d4][row] LDS layout).
// ---------------------------------------------------------------------------
__device__ __forceinline__ float norm64v(const float4* __restrict__ p) {
#pragma clang fp contract(off)
    float tt[64];
#pragma unroll
    for (int q = 0; q < 16; ++q) {
        float4 v = p[q];
        tt[4 * q + 0] = v.x * v.x;
        tt[4 * q + 1] = v.y * v.y;
        tt[4 * q + 2] = v.z * v.z;
        tt[4 * q + 3] = v.w * v.w;
    }
    float r[8];
#pragma unroll
    for (int j = 0; j < 8; ++j) r[j] = tt[j];
#pragma unroll
    for (int i = 8; i < 64; i += 8)
#pragma unroll
        for (int j = 0; j < 8; ++j) r[j] += tt[i + j];
    return ((r[0] + r[1]) + (r[2] + r[3])) + ((r[4] + r[5]) + (r[6] + r[7]));
}

__device__ __forceinline__ float norm64s(const float4* __restrict__ p) {
#pragma clang fp contract(off)
    float tt[64];
#pragma unroll
    for (int q = 0; q < 16; ++q) {
        float4 v = p[(size_t)q * 128];     // xs[d4][row]: row fixed, d4 = q
        tt[4 * q + 0] = v.x * v.x;
        tt[4 * q + 1] = v.y * v.y;
        tt[4 * q + 2] = v.z * v.z;
        tt[4 * q + 3] = v.w * v.w;
    }
    float r[8];
#pragma unroll
    for (int j = 0; j < 8; ++j) r[j] = tt[j];
#pragma unroll
    for (int i = 8; i < 64; i += 8)
#pragma unroll
        for (int j = 0; j < 8; ++j) r[j] += tt[i + j];
    return ((r[0] + r[1]) + (r[2] + r[3])) + ((r[4] + r[5]) + (r[6] + r[7]));
}

__device__ __forceinline__ uint32_t fsort(float f) {
    uint32_t b = __float_as_uint(f);
    return (b & 0x80000000u) ? ~b : (b | 0x80000000u);
}

// ---------------------------------------------------------------------------
// dist kernel v2 (scalar-pipe E): 2048 blocks = 256 rg x 8 cg; 256 thr.
// Wave w owns codes cg*128 + w*32 .. +31 (WAVE-UNIFORM) x all 128 rows; lane
// owns rows l and l+64. E-values are uniform -> s_load (SMEM pipe) and feed
// v_fmac as the SGPR operand; LDS only feeds X: 2 ds_read_b128/lane/d4
// (xs[d4][row]float4, contiguous 16B/lane). Per-CU LDS 98k->25k cyc; VALU
// floor ~27 us becomes the bound. FMA chain per (row,code) stays d-ascending
// fmaf -> bit-exact numpy argmin (ties to lowest code via packed u64 key).
// R1: no full K-unroll (spill). R3: per-lane VMEM e-loads are latency-bound.
// ---------------------------------------------------------------------------
__global__ __launch_bounds__(256, 4)
void dist_kernel(const float* __restrict__ z_e, const float* __restrict__ emb,
                 unsigned long long* __restrict__ minkey) {
    __shared__ float4 xs[16 * 128];                 // [d4][row], 32 KB
    __shared__ float An_s[128];
    __shared__ float Bn_s[128];
    __shared__ unsigned long long best4[4 * 128];   // [wave][row]
    const int tid = threadIdx.x;
    const int rg = blockIdx.x >> 3, cg = blockIdx.x & 7;
    const int n0 = rg * 128;
    const int b = n0 >> 10, hw0 = n0 & 1023;
    const float* zb = z_e + (size_t)b * 65536 + hw0;

    // stage x-tile: 4 coalesced d-slices per float4 LDS write
    {
        int hwi = tid & 127;
        int d4g = tid >> 7;   // 0..1
#pragma unroll
        for (int it = 0; it < 8; ++it) {
            int d4 = d4g + it * 2;
            int dbase = d4 * 4;
            float4 v;
            v.x = zb[(size_t)(dbase + 0) * 1024 + hwi];
            v.y = zb[(size_t)(dbase + 1) * 1024 + hwi];
            v.z = zb[(size_t)(dbase + 2) * 1024 + hwi];
            v.w = zb[(size_t)(dbase + 3) * 1024 + hwi];
            xs[d4 * 128 + hwi] = v;
        }
    }
    __syncthreads();

    // in-block norms: rows from LDS tile (same bits as global), codes from
    // global emb rows (R3/R5-verified identical bits).
    if (tid < 128) {
        An_s[tid] = norm64s(&xs[tid]);
    } else {
        int c = tid - 128;
        Bn_s[c] = norm64v((const float4*)(emb + (size_t)(cg * 128 + c) * 64));
    }
    __syncthreads();

    const int w = __builtin_amdgcn_readfirstlane(tid >> 6);   // wave id, uniform
    const int l = tid & 63;
    const int cb = cg * 128 + w * 32;        // global code base for this wave
    const float An0 = An_s[l];
    const float An1 = An_s[l + 64];
    const float* eb = emb + (size_t)cb * 64; // wave-uniform base -> SMEM

    unsigned long long b0 = ~0ULL, b1 = ~0ULL;

#pragma unroll 1
    for (int g = 0; g < 4; ++g) {            // 8 codes per group
        const float* eg = eb + g * 8 * 64;
        float a0[8], a1[8];
#pragma unroll
        for (int c = 0; c < 8; ++c) { a0[c] = 0.0f; a1[c] = 0.0f; }

#pragma unroll 2
        for (int d4 = 0; d4 < 16; ++d4) {
            float4 x0 = xs[d4 * 128 + l];
            float4 x1 = xs[d4 * 128 + l + 64];
#pragma unroll
            for (int c = 0; c < 8; ++c) {
                const float* ec = eg + c * 64 + d4 * 4;   // uniform -> s_load_dwordx4
                float e0 = ec[0], e1 = ec[1], e2 = ec[2], e3 = ec[3];
                float t0 = a0[c];
                t0 = __builtin_fmaf(x0.x, e0, t0);
                t0 = __builtin_fmaf(x0.y, e1, t0);
                t0 = __builtin_fmaf(x0.z, e2, t0);
                t0 = __builtin_fmaf(x0.w, e3, t0);
                a0[c] = t0;
                float t1 = a1[c];
                t1 = __builtin_fmaf(x1.x, e0, t1);
                t1 = __builtin_fmaf(x1.y, e1, t1);
                t1 = __builtin_fmaf(x1.z, e2, t1);
                t1 = __builtin_fmaf(x1.w, e3, t1);
                a1[c] = t1;
            }
        }
        // fold this group's 8 codes into the running per-row best
#pragma unroll
        for (int c = 0; c < 8; ++c) {
            float Bc = Bn_s[w * 32 + g * 8 + c];     // broadcast LDS read
            unsigned code = (unsigned)(cb + g * 8 + c);
            float s0 = An0 + Bc;                     // fl(A+B)
            float d0 = s0 - 2.0f * a0[c];            // fl(s - 2C), 2C exact
            unsigned long long k0 = ((unsigned long long)fsort(d0) << 32) | code;
            b0 = (k0 < b0) ? k0 : b0;
            float s1 = An1 + Bc;
            float d1 = s1 - 2.0f * a1[c];
            unsigned long long k1 = ((unsigned long long)fsort(d1) << 32) | code;
            b1 = (k1 < b1) ? k1 : b1;
        }
    }

    best4[w * 128 + l]      = b0;
    best4[w * 128 + l + 64] = b1;
    __syncthreads();
    if (tid < 128) {
        unsigned long long m = best4[tid];
#pragma unroll
        for (int ww = 1; ww < 4; ++ww) {
            unsigned long long o = best4[ww * 128 + tid];
            m = (o < m) ? o : m;
        }
        atomicMin(&minkey[n0 + tid], m);
    }
}

// ---------------------------------------------------------------------------
// finish kernel: grid 8192 x 256, 4 rows/block. minkey -> code; writes z_st
// (= z + fl(z_q - z)), one-hot encodings, PLAIN-STORE fp64 loss partial.
// No atomics at all (counts moved to scalar histogram).
// ---------------------------------------------------------------------------
__global__ void finish_kernel(const float* __restrict__ z_e,
                              const float* __restrict__ emb,
                              const unsigned long long* __restrict__ minkey,
                              double* __restrict__ lp,
                              float* __restrict__ out) {
    __shared__ uint32_t scode[4];
    __shared__ double lred[4];
    const int t = threadIdx.x;
    const int r4 = blockIdx.x * 4;                 // rows r4..r4+3 (same b)
    if (t < 4) scode[t] = (uint32_t)minkey[r4 + t];
    __syncthreads();

    // z_st + loss: 256 elems, thread t -> row r4+(t&3), d = t>>2
    {
        const int b = r4 >> 10, hw = (r4 & 1023) + (t & 3);
        const int d = t >> 2;
        const size_t off = (size_t)b * 65536 + (size_t)d * 1024 + hw;
        float z  = z_e[off];
        float zq = emb[(size_t)scode[t & 3] * 64 + d];
        float tt = zq - z;                 // fl(z_q - z), as in np
        out[off] = z + tt;                 // straight-through value
        double ls = (double)tt * (double)tt;
#pragma unroll
        for (int m = 32; m >= 1; m >>= 1) ls += __shfl_down(ls, m, 64);
        if ((t & 63) == 0) lred[t >> 6] = ls;
    }
    __syncthreads();
    if (t == 0) lp[blockIdx.x] = lred[0] + lred[1] + lred[2] + lred[3];

    // one-hot: 4 rows x 256 float4 (1KB contiguous per wave-instr)
    float* enc = out + OUT_ENC;
#pragma unroll
    for (int i = 0; i < 4; ++i) {
        uint32_t code = scode[i];
        uint32_t c0 = (uint32_t)(t * 4);
        float4 v;
        v.x = (code == c0 + 0u) ? 1.0f : 0.0f;
        v.y = (code == c0 + 1u) ? 1.0f : 0.0f;
        v.z = (code == c0 + 2u) ? 1.0f : 0.0f;
        v.w = (code == c0 + 3u) ? 1.0f : 0.0f;
        ((float4*)enc)[(size_t)(r4 + i) * 256 + t] = v;
    }
}

// ---------------------------------------------------------------------------
// scalar kernel: one block. Histograms minkey codes in LDS (replaces global
// counts + its memset), sums fp64 loss partials, computes loss & perplexity.
// Stream ordering provides coherence — no fences.
// ---------------------------------------------------------------------------
__global__ void scalar_kernel(const unsigned long long* __restrict__ minkey,
                              const double* __restrict__ lp,
                              float* __restrict__ out) {
    __shared__ uint32_t hist[Kk];
    __shared__ double redl[4], redh[4];
    const int t = threadIdx.x;   // 256
    for (int i = t; i < Kk; i += 256) hist[i] = 0;
    __syncthreads();
    for (int i = t; i < Nn; i += 256) atomicAdd(&hist[(uint32_t)minkey[i] & 1023u], 1u);
    __syncthreads();
    double ls = 0.0;
    for (int i = t; i < 8192; i += 256) ls += lp[i];
    double h = 0.0;
    for (int i = t; i < Kk; i += 256) {
        double p = (double)hist[i] * (1.0 / 32768.0);
        h += p * log(p + 1e-10);
    }
#pragma unroll
    for (int m = 32; m >= 1; m >>= 1) { ls += __shfl_down(ls, m, 64); h += __shfl_down(h, m, 64); }
    if ((t & 63) == 0) { redl[t >> 6] = ls; redh[t >> 6] = h; }
    __syncthreads();
    if (t == 0) {
        double L = redl[0] + redl[1] + redl[2] + redl[3];
        double H = redh[0] + redh[1] + redh[2] + redh[3];
        out[OUT_PERP] = (float)exp(-H);
        float m32 = (float)(L * (1.0 / 2097152.0));
        out[OUT_LOSS] = m32 + 0.25f * m32;   // q + 0.25*e, q==e numerically
    }
}

extern "C" void kernel_launch(void* const* d_in, const int* in_sizes, int n_in,
                              void* d_out, int out_size, void* d_ws, size_t ws_size,
                              hipStream_t stream) {
    const float* z_e = (const float*)d_in[0];
    const float* emb = (const float*)d_in[1];
    float* out = (float*)d_out;
    char* ws = (char*)d_ws;

    double* lp = (double*)(ws + WS_LP);
    unsigned long long* minkey = (unsigned long long*)(ws + WS_KEY);

    // ws poisoned 0xAA every call: 0xFF the minkeys (atomicMin identity)
    hipMemsetAsync(ws + WS_KEY, 0xFF, (size_t)Nn * 8, stream);

    dist_kernel<<<2048, 256, 0, stream>>>(z_e, emb, minkey);
    finish_kernel<<<8192, 256, 0, stream>>>(z_e, emb, minkey, lp, out);
    scalar_kernel<<<1, 256, 0, stream>>>(minkey, lp, out);
}

// Round 7
// 265.587 us; speedup vs baseline: 1.2696x; 1.2696x over previous
//
#include <hip/hip_runtime.h>
#include <stdint.h>
#include <math.h>

// Problem constants
constexpr int Nn  = 32768;          // B*H*W = 32*32*32
constexpr int Kk  = 1024;

// d_out layout (floats)
constexpr int OUT0_N   = 32 * 64 * 1024;       // 2097152 (z_st, [B,D,H,W])
constexpr int OUT_LOSS = OUT0_N;               // 2097152
constexpr int OUT_PERP = OUT0_N + 1;           // 2097153
constexpr int OUT_ENC  = OUT0_N + 2;           // 2097154

// d_ws layout (bytes):
//   [0     .. 65536)  loss partials double[8192] (fully written by finish)
//   [65536 .. 327680) minkey u64[32768]          (memset 0xFF — real keys are
//                      ~0xC2..<<32, so 0xAA poison is NOT a min-identity)
// R4 lesson: no single-address atomics at grid scale.
constexpr size_t WS_LP  = 0;
constexpr size_t WS_KEY = 65536;

// ---------------------------------------------------------------------------
// numpy-bit-exact 64-elem squared-norm: tt[d]=fl(x*x), 8 stride-8 sequential
// accumulators, pairwise combine. Contraction OFF. p: 16B-aligned, contiguous.
// ---------------------------------------------------------------------------
__device__ __forceinline__ float norm64v(const float4* __restrict__ p) {
#pragma clang fp contract(off)
    float tt[64];
#pragma unroll
    for (int q = 0; q < 16; ++q) {
        float4 v = p[q];
        tt[4 * q + 0] = v.x * v.x;
        tt[4 * q + 1] = v.y * v.y;
        tt[4 * q + 2] = v.z * v.z;
        tt[4 * q + 3] = v.w * v.w;
    }
    float r[8];
#pragma unroll
    for (int j = 0; j < 8; ++j) r[j] = tt[j];
#pragma unroll
    for (int i = 8; i < 64; i += 8)
#pragma unroll
        for (int j = 0; j < 8; ++j) r[j] += tt[i + j];
    return ((r[0] + r[1]) + (r[2] + r[3])) + ((r[4] + r[5]) + (r[6] + r[7]));
}

__device__ __forceinline__ uint32_t fsort(float f) {
    uint32_t b = __float_as_uint(f);
    return (b & 0x80000000u) ? ~b : (b | 0x80000000u);
}

// ---------------------------------------------------------------------------
// dist kernel — all-LDS (R4 structure, measured ~55-60 us):
// 2048 blocks = 256 rowgroups x 8 codegroups; 256 thr (16x16); per-thread 8x8;
// both tiles in LDS (stride 68, conflict-free). unroll-1 K-loop (R1: full
// unroll spilled acc -> 4.9 GB scratch). Winner via atomicMin on packed u64
// key (32768 distinct addresses, 8-way contention — cheap).
// R3+R6 lesson: e-operand via per-lane VMEM (R3) or wave-uniform SMEM (R6)
// is latency-bound (~150 us both). Both operands MUST come from LDS.
// LDS-pipe floor: 8 blk/CU x 1024 ds_read_b128 x 12 cyc = 41 us.
// ---------------------------------------------------------------------------
__global__ __launch_bounds__(256, 2)
void dist_kernel(const float* __restrict__ z_e, const float* __restrict__ emb,
                 unsigned long long* __restrict__ minkey) {
    __shared__ float xs[128 * 68];   // [row][d]
    __shared__ float es[128 * 68];   // [code][d]
    __shared__ float An_s[128];
    __shared__ float Bn_s[128];
    const int tid = threadIdx.x;
    const int rg = blockIdx.x >> 3, cg = blockIdx.x & 7;
    const int n0 = rg * 128;
    const int b = n0 >> 10, hw0 = n0 & 1023;
    const float* zb = z_e + (size_t)b * 65536 + hw0;

    // stage x-tile: 4 coalesced d-slices per float4 LDS write
    {
        int hwi = tid & 127;
        int d4g = tid >> 7;   // 0..1
#pragma unroll
        for (int it = 0; it < 8; ++it) {
            int dbase = (d4g + it * 2) * 4;
            float4 v;
            v.x = zb[(size_t)(dbase + 0) * 1024 + hwi];
            v.y = zb[(size_t)(dbase + 1) * 1024 + hwi];
            v.z = zb[(size_t)(dbase + 2) * 1024 + hwi];
            v.w = zb[(size_t)(dbase + 3) * 1024 + hwi];
            *(float4*)&xs[hwi * 68 + dbase] = v;
        }
    }
    // stage e-tile: contiguous 32KB, coalesced float4
    {
        const float4* ep = (const float4*)(emb + (size_t)cg * 128 * 64);
#pragma unroll
        for (int it = 0; it < 8; ++it) {
            int j = tid + it * 256;      // 0..2047
            float4 v = ep[j];
            int c = j >> 4, d4 = j & 15;
            *(float4*)&es[c * 68 + d4 * 4] = v;
        }
    }
    __syncthreads();

    // in-block norms from the staged tiles (identical bits to global)
    if (tid < 128) {
        An_s[tid] = norm64v((const float4*)&xs[tid * 68]);
    } else {
        int c = tid - 128;
        Bn_s[c] = norm64v((const float4*)&es[c * 68]);
    }
    __syncthreads();

    const int tx = tid & 15, ty = tid >> 4;
    float acc[8][8];
#pragma unroll
    for (int i = 0; i < 8; ++i)
#pragma unroll
        for (int j = 0; j < 8; ++j) acc[i][j] = 0.0f;

#pragma unroll 1
    for (int d4 = 0; d4 < 16; ++d4) {
        float4 xv[8], ev[8];
#pragma unroll
        for (int i = 0; i < 8; ++i) xv[i] = *(const float4*)&xs[(ty + 16 * i) * 68 + d4 * 4];
#pragma unroll
        for (int j = 0; j < 8; ++j) ev[j] = *(const float4*)&es[(tx + 16 * j) * 68 + d4 * 4];
#pragma unroll
        for (int i = 0; i < 8; ++i)
#pragma unroll
            for (int j = 0; j < 8; ++j) {
                float a = acc[i][j];
                a = __builtin_fmaf(xv[i].x, ev[j].x, a);
                a = __builtin_fmaf(xv[i].y, ev[j].y, a);
                a = __builtin_fmaf(xv[i].z, ev[j].z, a);
                a = __builtin_fmaf(xv[i].w, ev[j].w, a);
                acc[i][j] = a;
            }
    }

    // epilogue: dist = fl(fl(A+B) - 2C); per-row min over this block's codes
    float Ar[8], Bc[8];
#pragma unroll
    for (int i = 0; i < 8; ++i) Ar[i] = An_s[ty + 16 * i];
#pragma unroll
    for (int j = 0; j < 8; ++j) Bc[j] = Bn_s[tx + 16 * j];

#pragma unroll
    for (int i = 0; i < 8; ++i) {
        unsigned long long best = ~0ULL;
#pragma unroll
        for (int j = 0; j < 8; ++j) {
            float s = Ar[i] + Bc[j];
            float dist = s - 2.0f * acc[i][j];
            unsigned long long key = ((unsigned long long)fsort(dist) << 32)
                                   | (unsigned)(cg * 128 + tx + 16 * j);
            best = (key < best) ? key : best;
        }
#pragma unroll
        for (int m = 1; m < 16; m <<= 1) {
            unsigned long long o = __shfl_xor(best, m, 64);
            best = (o < best) ? o : best;
        }
        if (tx == 0) atomicMin(&minkey[n0 + ty + 16 * i], best);
    }
}

// ---------------------------------------------------------------------------
// finish kernel: grid 8192 x 256, 4 rows/block. minkey -> code; writes z_st
// (= z + fl(z_q - z)), one-hot encodings, PLAIN-STORE fp64 loss partial.
// No atomics at all (R4 lesson; counts moved to scalar's LDS histogram).
// ---------------------------------------------------------------------------
__global__ void finish_kernel(const float* __restrict__ z_e,
                              const float* __restrict__ emb,
                              const unsigned long long* __restrict__ minkey,
                              double* __restrict__ lp,
                              float* __restrict__ out) {
    __shared__ uint32_t scode[4];
    __shared__ double lred[4];
    const int t = threadIdx.x;
    const int r4 = blockIdx.x * 4;                 // rows r4..r4+3 (same b)
    if (t < 4) scode[t] = (uint32_t)minkey[r4 + t];
    __syncthreads();

    // z_st + loss: 256 elems, thread t -> row r4+(t&3), d = t>>2
    {
        const int b = r4 >> 10, hw = (r4 & 1023) + (t & 3);
        const int d = t >> 2;
        const size_t off = (size_t)b * 65536 + (size_t)d * 1024 + hw;
        float z  = z_e[off];
        float zq = emb[(size_t)scode[t & 3] * 64 + d];
        float tt = zq - z;                 // fl(z_q - z), as in np
        out[off] = z + tt;                 // straight-through value
        double ls = (double)tt * (double)tt;
#pragma unroll
        for (int m = 32; m >= 1; m >>= 1) ls += __shfl_down(ls, m, 64);
        if ((t & 63) == 0) lred[t >> 6] = ls;
    }
    __syncthreads();
    if (t == 0) lp[blockIdx.x] = lred[0] + lred[1] + lred[2] + lred[3];

    // one-hot: 4 rows x 256 float4 (1KB contiguous per wave-instr)
    float* enc = out + OUT_ENC;
#pragma unroll
    for (int i = 0; i < 4; ++i) {
        uint32_t code = scode[i];
        uint32_t c0 = (uint32_t)(t * 4);
        float4 v;
        v.x = (code == c0 + 0u) ? 1.0f : 0.0f;
        v.y = (code == c0 + 1u) ? 1.0f : 0.0f;
        v.z = (code == c0 + 2u) ? 1.0f : 0.0f;
        v.w = (code == c0 + 3u) ? 1.0f : 0.0f;
        ((float4*)enc)[(size_t)(r4 + i) * 256 + t] = v;
    }
}

// ---------------------------------------------------------------------------
// scalar kernel: one block. Histograms minkey codes in LDS, sums fp64 loss
// partials, computes loss & perplexity. Stream ordering provides coherence.
// ---------------------------------------------------------------------------
__global__ void scalar_kernel(const unsigned long long* __restrict__ minkey,
                              const double* __restrict__ lp,
                              float* __restrict__ out) {
    __shared__ uint32_t hist[Kk];
    __shared__ double redl[4], redh[4];
    const int t = threadIdx.x;   // 256
    for (int i = t; i < Kk; i += 256) hist[i] = 0;
    __syncthreads();
    for (int i = t; i < Nn; i += 256) atomicAdd(&hist[(uint32_t)minkey[i] & 1023u], 1u);
    __syncthreads();
    double ls = 0.0;
    for (int i = t; i < 8192; i += 256) ls += lp[i];
    double h = 0.0;
    for (int i = t; i < Kk; i += 256) {
        double p = (double)hist[i] * (1.0 / 32768.0);
        h += p * log(p + 1e-10);
    }
#pragma unroll
    for (int m = 32; m >= 1; m >>= 1) { ls += __shfl_down(ls, m, 64); h += __shfl_down(h, m, 64); }
    if ((t & 63) == 0) { redl[t >> 6] = ls; redh[t >> 6] = h; }
    __syncthreads();
    if (t == 0) {
        double L = redl[0] + redl[1] + redl[2] + redl[3];
        double H = redh[0] + redh[1] + redh[2] + redh[3];
        out[OUT_PERP] = (float)exp(-H);
        float m32 = (float)(L * (1.0 / 2097152.0));
        out[OUT_LOSS] = m32 + 0.25f * m32;   // q + 0.25*e, q==e numerically
    }
}

extern "C" void kernel_launch(void* const* d_in, const int* in_sizes, int n_in,
                              void* d_out, int out_size, void* d_ws, size_t ws_size,
                              hipStream_t stream) {
    const float* z_e = (const float*)d_in[0];
    const float* emb = (const float*)d_in[1];
    float* out = (float*)d_out;
    char* ws = (char*)d_ws;

    double* lp = (double*)(ws + WS_LP);
    unsigned long long* minkey = (unsigned long long*)(ws + WS_KEY);

    // ws poisoned 0xAA every call: 0xFF the minkeys (atomicMin identity)
    hipMemsetAsync(ws + WS_KEY, 0xFF, (size_t)Nn * 8, stream);

    dist_kernel<<<2048, 256, 0, stream>>>(z_e, emb, minkey);
    finish_kernel<<<8192, 256, 0, stream>>>(z_e, emb, minkey, lp, out);
    scalar_kernel<<<1, 256, 0, stream>>>(minkey, lp, out);
}

// Round 8
// 236.632 us; speedup vs baseline: 1.4249x; 1.1224x over previous
//
#include <hip/hip_runtime.h>
#include <stdint.h>
#include <math.h>

// Problem constants
constexpr int Nn  = 32768;          // B*H*W = 32*32*32
constexpr int Kk  = 1024;

// d_out layout (floats)
constexpr int OUT0_N   = 32 * 64 * 1024;       // 2097152 (z_st, [B,D,H,W])
constexpr int OUT_LOSS = OUT0_N;               // 2097152
constexpr int OUT_PERP = OUT0_N + 1;           // 2097153
constexpr int OUT_ENC  = OUT0_N + 2;           // 2097154

// d_ws layout (bytes):
//   [0      .. 4096)   counts u32[1024]           (memset 0)
//   [4096   .. 69632)  loss partials double[8192] (fully written by finish)
//   [69632  .. 331776) minkey u64[32768]          (memset 0xFF — real keys are
//                      ~0xC2..<<32, so 0xAA poison is NOT a min-identity)
// R4 lesson: no single-address atomics at grid scale.
// R7 lesson: single-block 256KB histogram scan is latency-bound (~+25 us);
// spread counts atomics in finish (R5) are free.
constexpr size_t WS_CNT = 0;
constexpr size_t WS_LP  = 4096;
constexpr size_t WS_KEY = 69632;

// ---------------------------------------------------------------------------
// numpy-bit-exact 64-elem squared-norm: tt[d]=fl(x*x), 8 stride-8 sequential
// accumulators, pairwise combine. Contraction OFF. p: 16B-aligned, contiguous.
// ---------------------------------------------------------------------------
__device__ __forceinline__ float norm64v(const float4* __restrict__ p) {
#pragma clang fp contract(off)
    float tt[64];
#pragma unroll
    for (int q = 0; q < 16; ++q) {
        float4 v = p[q];
        tt[4 * q + 0] = v.x * v.x;
        tt[4 * q + 1] = v.y * v.y;
        tt[4 * q + 2] = v.z * v.z;
        tt[4 * q + 3] = v.w * v.w;
    }
    float r[8];
#pragma unroll
    for (int j = 0; j < 8; ++j) r[j] = tt[j];
#pragma unroll
    for (int i = 8; i < 64; i += 8)
#pragma unroll
        for (int j = 0; j < 8; ++j) r[j] += tt[i + j];
    return ((r[0] + r[1]) + (r[2] + r[3])) + ((r[4] + r[5]) + (r[6] + r[7]));
}

__device__ __forceinline__ uint32_t fsort(float f) {
    uint32_t b = __float_as_uint(f);
    return (b & 0x80000000u) ? ~b : (b | 0x80000000u);
}

// ---------------------------------------------------------------------------
// dist kernel — all-LDS (R4 structure, measured ~55-60 us):
// 2048 blocks = 256 rowgroups x 8 codegroups; 256 thr (16x16); per-thread 8x8;
// both tiles in LDS (stride 68, conflict-free). unroll-1 K-loop (R1: full
// unroll spilled acc -> 4.9 GB scratch). Winner via atomicMin on packed u64
// key (32768 distinct addresses, 8-way contention — cheap).
// R3+R6 lesson: e-operand via per-lane VMEM (R3) or wave-uniform SMEM (R6)
// is latency-bound (~150 us both). Both operands MUST come from LDS.
// Structural floors: LDS pipe 41 us, VALU 27 us — measured ~55 is floor+
// staging/barrier overhead. 8x8 tile is minimal LDS-instr/FMA without spill.
// ---------------------------------------------------------------------------
__global__ __launch_bounds__(256, 2)
void dist_kernel(const float* __restrict__ z_e, const float* __restrict__ emb,
                 unsigned long long* __restrict__ minkey) {
    __shared__ float xs[128 * 68];   // [row][d]
    __shared__ float es[128 * 68];   // [code][d]
    __shared__ float An_s[128];
    __shared__ float Bn_s[128];
    const int tid = threadIdx.x;
    const int rg = blockIdx.x >> 3, cg = blockIdx.x & 7;
    const int n0 = rg * 128;
    const int b = n0 >> 10, hw0 = n0 & 1023;
    const float* zb = z_e + (size_t)b * 65536 + hw0;

    // stage x-tile: 4 coalesced d-slices per float4 LDS write
    {
        int hwi = tid & 127;
        int d4g = tid >> 7;   // 0..1
#pragma unroll
        for (int it = 0; it < 8; ++it) {
            int dbase = (d4g + it * 2) * 4;
            float4 v;
            v.x = zb[(size_t)(dbase + 0) * 1024 + hwi];
            v.y = zb[(size_t)(dbase + 1) * 1024 + hwi];
            v.z = zb[(size_t)(dbase + 2) * 1024 + hwi];
            v.w = zb[(size_t)(dbase + 3) * 1024 + hwi];
            *(float4*)&xs[hwi * 68 + dbase] = v;
        }
    }
    // stage e-tile: contiguous 32KB, coalesced float4
    {
        const float4* ep = (const float4*)(emb + (size_t)cg * 128 * 64);
#pragma unroll
        for (int it = 0; it < 8; ++it) {
            int j = tid + it * 256;      // 0..2047
            float4 v = ep[j];
            int c = j >> 4, d4 = j & 15;
            *(float4*)&es[c * 68 + d4 * 4] = v;
        }
    }
    __syncthreads();

    // in-block norms from the staged tiles (identical bits to global)
    if (tid < 128) {
        An_s[tid] = norm64v((const float4*)&xs[tid * 68]);
    } else {
        int c = tid - 128;
        Bn_s[c] = norm64v((const float4*)&es[c * 68]);
    }
    __syncthreads();

    const int tx = tid & 15, ty = tid >> 4;
    float acc[8][8];
#pragma unroll
    for (int i = 0; i < 8; ++i)
#pragma unroll
        for (int j = 0; j < 8; ++j) acc[i][j] = 0.0f;

#pragma unroll 1
    for (int d4 = 0; d4 < 16; ++d4) {
        float4 xv[8], ev[8];
#pragma unroll
        for (int i = 0; i < 8; ++i) xv[i] = *(const float4*)&xs[(ty + 16 * i) * 68 + d4 * 4];
#pragma unroll
        for (int j = 0; j < 8; ++j) ev[j] = *(const float4*)&es[(tx + 16 * j) * 68 + d4 * 4];
#pragma unroll
        for (int i = 0; i < 8; ++i)
#pragma unroll
            for (int j = 0; j < 8; ++j) {
                float a = acc[i][j];
                a = __builtin_fmaf(xv[i].x, ev[j].x, a);
                a = __builtin_fmaf(xv[i].y, ev[j].y, a);
                a = __builtin_fmaf(xv[i].z, ev[j].z, a);
                a = __builtin_fmaf(xv[i].w, ev[j].w, a);
                acc[i][j] = a;
            }
    }

    // epilogue: dist = fl(fl(A+B) - 2C); per-row min over this block's codes
    float Ar[8], Bc[8];
#pragma unroll
    for (int i = 0; i < 8; ++i) Ar[i] = An_s[ty + 16 * i];
#pragma unroll
    for (int j = 0; j < 8; ++j) Bc[j] = Bn_s[tx + 16 * j];

#pragma unroll
    for (int i = 0; i < 8; ++i) {
        unsigned long long best = ~0ULL;
#pragma unroll
        for (int j = 0; j < 8; ++j) {
            float s = Ar[i] + Bc[j];
            float dist = s - 2.0f * acc[i][j];
            unsigned long long key = ((unsigned long long)fsort(dist) << 32)
                                   | (unsigned)(cg * 128 + tx + 16 * j);
            best = (key < best) ? key : best;
        }
#pragma unroll
        for (int m = 1; m < 16; m <<= 1) {
            unsigned long long o = __shfl_xor(best, m, 64);
            best = (o < best) ? o : best;
        }
        if (tx == 0) atomicMin(&minkey[n0 + ty + 16 * i], best);
    }
}

// ---------------------------------------------------------------------------
// finish kernel: grid 8192 x 256, 4 rows/block. minkey -> code; writes z_st
// (= z + fl(z_q - z)), one-hot encodings, PLAIN-STORE fp64 loss partial, and
// 4 spread atomicAdds into counts[1024] (R5: measured-cheap).
// ---------------------------------------------------------------------------
__global__ void finish_kernel(const float* __restrict__ z_e,
                              const float* __restrict__ emb,
                              const unsigned long long* __restrict__ minkey,
                              uint32_t* __restrict__ counts,
                              double* __restrict__ lp,
                              float* __restrict__ out) {
    __shared__ uint32_t scode[4];
    __shared__ double lred[4];
    const int t = threadIdx.x;
    const int r4 = blockIdx.x * 4;                 // rows r4..r4+3 (same b)
    if (t < 4) {
        uint32_t code = (uint32_t)minkey[r4 + t];
        scode[t] = code;
        atomicAdd(&counts[code], 1u);
    }
    __syncthreads();

    // z_st + loss: 256 elems, thread t -> row r4+(t&3), d = t>>2
    {
        const int b = r4 >> 10, hw = (r4 & 1023) + (t & 3);
        const int d = t >> 2;
        const size_t off = (size_t)b * 65536 + (size_t)d * 1024 + hw;
        float z  = z_e[off];
        float zq = emb[(size_t)scode[t & 3] * 64 + d];
        float tt = zq - z;                 // fl(z_q - z), as in np
        out[off] = z + tt;                 // straight-through value
        double ls = (double)tt * (double)tt;
#pragma unroll
        for (int m = 32; m >= 1; m >>= 1) ls += __shfl_down(ls, m, 64);
        if ((t & 63) == 0) lred[t >> 6] = ls;
    }
    __syncthreads();
    if (t == 0) lp[blockIdx.x] = lred[0] + lred[1] + lred[2] + lred[3];

    // one-hot: 4 rows x 256 float4 (1KB contiguous per wave-instr)
    float* enc = out + OUT_ENC;
#pragma unroll
    for (int i = 0; i < 4; ++i) {
        uint32_t code = scode[i];
        uint32_t c0 = (uint32_t)(t * 4);
        float4 v;
        v.x = (code == c0 + 0u) ? 1.0f : 0.0f;
        v.y = (code == c0 + 1u) ? 1.0f : 0.0f;
        v.z = (code == c0 + 2u) ? 1.0f : 0.0f;
        v.w = (code == c0 + 3u) ? 1.0f : 0.0f;
        ((float4*)enc)[(size_t)(r4 + i) * 256 + t] = v;
    }
}

// ---------------------------------------------------------------------------
// scalar kernel: one block; sums counts entropy (4KB) + fp64 loss partials
// (64KB). Stream ordering provides coherence — no fences.
// ---------------------------------------------------------------------------
__global__ void scalar_kernel(const uint32_t* __restrict__ counts,
                              const double* __restrict__ lp,
                              float* __restrict__ out) {
    __shared__ double redl[4], redh[4];
    const int t = threadIdx.x;   // 256
    double ls = 0.0;
    for (int i = t; i < 8192; i += 256) ls += lp[i];
    double h = 0.0;
    for (int i = t; i < Kk; i += 256) {
        double p = (double)counts[i] * (1.0 / 32768.0);
        h += p * log(p + 1e-10);
    }
#pragma unroll
    for (int m = 32; m >= 1; m >>= 1) { ls += __shfl_down(ls, m, 64); h += __shfl_down(h, m, 64); }
    if ((t & 63) == 0) { redl[t >> 6] = ls; redh[t >> 6] = h; }
    __syncthreads();
    if (t == 0) {
        double L = redl[0] + redl[1] + redl[2] + redl[3];
        double H = redh[0] + redh[1] + redh[2] + redh[3];
        out[OUT_PERP] = (float)exp(-H);
        float m32 = (float)(L * (1.0 / 2097152.0));
        out[OUT_LOSS] = m32 + 0.25f * m32;   // q + 0.25*e, q==e numerically
    }
}

extern "C" void kernel_launch(void* const* d_in, const int* in_sizes, int n_in,
                              void* d_out, int out_size, void* d_ws, size_t ws_size,
                              hipStream_t stream) {
    const float* z_e = (const float*)d_in[0];
    const float* emb = (const float*)d_in[1];
    float* out = (float*)d_out;
    char* ws = (char*)d_ws;

    uint32_t* counts = (uint32_t*)(ws + WS_CNT);
    double*   lp     = (double*)(ws + WS_LP);
    unsigned long long* minkey = (unsigned long long*)(ws + WS_KEY);

    // ws poisoned 0xAA every call: zero counts, 0xFF the minkeys
    hipMemsetAsync(ws + WS_CNT, 0, 4096, stream);
    hipMemsetAsync(ws + WS_KEY, 0xFF, (size_t)Nn * 8, stream);

    dist_kernel<<<2048, 256, 0, stream>>>(z_e, emb, minkey);
    finish_kernel<<<8192, 256, 0, stream>>>(z_e, emb, minkey, counts, lp, out);
    scalar_kernel<<<1, 256, 0, stream>>>(counts, lp, out);
}